// Round 4
// baseline (51.199 us; speedup 1.0000x reference)
//
#include <hip/hip_runtime.h>
#include <hip/hip_bf16.h>
#include <cstdint>
#include <cstddef>

using short8  = __attribute__((ext_vector_type(8))) short;
using short4v = __attribute__((ext_vector_type(4))) short;
using f32x4   = __attribute__((ext_vector_type(4))) float;

constexpr int NB = 16, NC = 512, ND = 256, NK = 32;
constexpr int ROWS = 16;               // rows per block (MFMA path)
constexpr int NROW = NB * NC;          // 8192
constexpr int NBLK = NROW / ROWS;      // 512
constexpr int LDP  = ND + 8;           // ushort row stride: 528 B (16B-aligned)

// packed bf16 weight layout in d_ws (element offsets):
//  vW frags: [0, 65536)        fragment fl = nt*8  + ks
//  oW frags: [65536, 131072)
//  gW frags: [131072, 262144)  fragment fl = nt*16 + ks (ks 0..7 h-half, 8..15 agg-half)
// within fragment: elem = (fl_global*64 + lane)*8 + j == W[ks*32 + (lane>>4)*8 + j][nt*16 + (lane&15)]
constexpr int PVW = 0;
constexpr int POW = 65536;
constexpr int PGW = 131072;
constexpr size_t WS_NEED = 262144ull * 2;

static __device__ __forceinline__ unsigned short f2bf(float f) {
    __hip_bfloat16 b = __float2bfloat16(f);
    return *reinterpret_cast<unsigned short*>(&b);
}
static __device__ __forceinline__ short4v f2bf4(float4 v) {
    short4v r;
    r[0] = (short)f2bf(v.x); r[1] = (short)f2bf(v.y);
    r[2] = (short)f2bf(v.z); r[3] = (short)f2bf(v.w);
    return r;
}

// ---------------------------------------------------------------------------
// prep: pack vW/oW/gW (f32 row-major [K][N]) into fragment-major bf16
// ---------------------------------------------------------------------------
__global__ __launch_bounds__(256)
void stk_pack(const float* __restrict__ vW, const float* __restrict__ oW,
              const float* __restrict__ gW, unsigned short* __restrict__ ws)
{
    const int tid  = blockIdx.x * 256 + threadIdx.x;   // 32768 threads
    const int lane = tid & 63;
    const int fl   = tid >> 6;                         // fragment id 0..511
    const float* src; int nt, ks;
    if (fl < 128)      { src = vW; nt = fl >> 3;         ks = fl & 7;          }
    else if (fl < 256) { src = oW; nt = (fl - 128) >> 3; ks = (fl - 128) & 7;  }
    else               { src = gW; nt = (fl - 256) >> 4; ks = (fl - 256) & 15; }
    const int col = nt * 16 + (lane & 15);
    const int k0  = ks * 32 + (lane >> 4) * 8;
    short8 v;
    #pragma unroll
    for (int j = 0; j < 8; ++j)
        v[j] = (short)f2bf(src[(size_t)(k0 + j) * ND + col]);
    *reinterpret_cast<short8*>(&ws[(size_t)tid * 8]) = v;
}

// ---------------------------------------------------------------------------
// main fused kernel (MFMA path): 16 rows/block, 256 threads (4 waves)
// ---------------------------------------------------------------------------
__global__ __launch_bounds__(256, 2)
void stk_mfma(const float* __restrict__ h,
              const int*   __restrict__ topk_idx,
              const float* __restrict__ topk_scores,
              const float* __restrict__ vb, const float* __restrict__ ob,
              const float* __restrict__ gb,
              const unsigned short* __restrict__ wsb,
              float* __restrict__ out)
{
    __shared__ float2 s_ai[ROWS][NK];                            // (attn, byte-ofs)
    __shared__ __align__(16) unsigned short s_w [ROWS][LDP];     // wsum bf16
    __shared__ __align__(16) unsigned short s_hb[ROWS][LDP];     // h    bf16
    __shared__ __align__(16) unsigned short s_ab[ROWS][LDP];     // agg  bf16

    const int t  = threadIdx.x;
    const int m0 = blockIdx.x * ROWS;
    const char* hB = (const char*)h + (size_t)(m0 >> 9) * ((size_t)NC * ND * 4);

    // ---------------- phase 1: softmax over K (width-32) --------------------
    {
        const int k  = t & 31;
        const int r0 = t >> 5;                        // 0..7
        #pragma unroll
        for (int half = 0; half < 2; ++half) {
            const int r = r0 + (half << 3);
            const size_t off = (size_t)(m0 + r) * NK + k;
            const float s = topk_scores[off];
            const int  id = topk_idx[off];
            float m = s;
            #pragma unroll
            for (int msk = 16; msk >= 1; msk >>= 1)
                m = fmaxf(m, __shfl_xor(m, msk));
            const float p = __expf(s - m);
            float Z = p;
            #pragma unroll
            for (int msk = 16; msk >= 1; msk >>= 1)
                Z += __shfl_xor(Z, msk);
            s_ai[r][k] = make_float2(p / Z, __int_as_float(id << 10)); // id*1024 bytes
        }
    }
    __syncthreads();

    const int lane = t & 63;
    const int w    = t >> 6;          // wave 0..3
    const int boff = lane * 16;       // byte offset of this lane's 4 columns

    // -------- phase 2: stage h rows (issue early) + float4 gather -----------
    {
        float4 hreg[4];
        #pragma unroll
        for (int i = 0; i < 4; ++i)
            hreg[i] = *reinterpret_cast<const float4*>(
                (const char*)h + ((size_t)(m0 + 4 * w + i) * ND * 4) + boff);

        #pragma unroll 1
        for (int i = 0; i < 4; ++i) {
            const int r = 4 * w + i;
            float4 a = {0.f, 0.f, 0.f, 0.f};
            #pragma unroll 8
            for (int k = 0; k < NK; ++k) {
                const float2 ai = s_ai[r][k];
                const float4 v  = *reinterpret_cast<const float4*>(
                    hB + (size_t)(unsigned)__float_as_int(ai.y) + boff);
                a.x = fmaf(ai.x, v.x, a.x);
                a.y = fmaf(ai.x, v.y, a.y);
                a.z = fmaf(ai.x, v.z, a.z);
                a.w = fmaf(ai.x, v.w, a.w);
            }
            *reinterpret_cast<short4v*>(&s_w[r][lane * 4]) = f2bf4(a);
        }
        #pragma unroll
        for (int i = 0; i < 4; ++i)
            *reinterpret_cast<short4v*>(&s_hb[4 * w + i][lane * 4]) = f2bf4(hreg[i]);
    }
    __syncthreads();

    const int lr = lane & 15;
    const int lg = lane >> 4;

    // ---------------- phase 3: agg = wsum @ vW + vb (MFMA) ------------------
    {
        f32x4 acc[4];
        #pragma unroll
        for (int n = 0; n < 4; ++n) {
            const float bv = vb[(4 * w + n) * 16 + lr];
            acc[n] = f32x4{bv, bv, bv, bv};
        }
        #pragma unroll
        for (int ks = 0; ks < 8; ++ks) {
            const int kb = ks * 32 + lg * 8;
            const short8 a = *reinterpret_cast<const short8*>(&s_w[lr][kb]);
            #pragma unroll
            for (int n = 0; n < 4; ++n) {
                const int nt = 4 * w + n;
                const short8 b = *reinterpret_cast<const short8*>(
                    &wsb[(size_t)(PVW + ((nt * 8 + ks) * 64 + lane) * 8)]);
                acc[n] = __builtin_amdgcn_mfma_f32_16x16x32_bf16(a, b, acc[n], 0, 0, 0);
            }
        }
        #pragma unroll
        for (int n = 0; n < 4; ++n) {
            const int col = (4 * w + n) * 16 + lr;
            #pragma unroll
            for (int r = 0; r < 4; ++r)
                s_ab[4 * lg + r][col] = f2bf(acc[n][r]);
        }
    }
    __syncthreads();

    // ------ phase 4: o = agg@oW + ob ; g = h@gW_h + agg@gW_a + gb -----------
    {
        f32x4 ao[4], ag[4];
        #pragma unroll
        for (int n = 0; n < 4; ++n) {
            const float bo = ob[(4 * w + n) * 16 + lr];
            const float bg = gb[(4 * w + n) * 16 + lr];
            ao[n] = f32x4{bo, bo, bo, bo};
            ag[n] = f32x4{bg, bg, bg, bg};
        }
        #pragma unroll
        for (int ks = 0; ks < 8; ++ks) {
            const int kb = ks * 32 + lg * 8;
            const short8 aa = *reinterpret_cast<const short8*>(&s_ab[lr][kb]);
            const short8 ah = *reinterpret_cast<const short8*>(&s_hb[lr][kb]);
            #pragma unroll
            for (int n = 0; n < 4; ++n) {
                const int nt = 4 * w + n;
                const short8 b_o  = *reinterpret_cast<const short8*>(
                    &wsb[(size_t)(POW + ((nt * 8 + ks) * 64 + lane) * 8)]);
                const short8 b_g1 = *reinterpret_cast<const short8*>(
                    &wsb[(size_t)(PGW + ((nt * 16 + ks) * 64 + lane) * 8)]);
                const short8 b_g2 = *reinterpret_cast<const short8*>(
                    &wsb[(size_t)(PGW + ((nt * 16 + ks + 8) * 64 + lane) * 8)]);
                ao[n] = __builtin_amdgcn_mfma_f32_16x16x32_bf16(aa, b_o,  ao[n], 0, 0, 0);
                ag[n] = __builtin_amdgcn_mfma_f32_16x16x32_bf16(ah, b_g1, ag[n], 0, 0, 0);
                ag[n] = __builtin_amdgcn_mfma_f32_16x16x32_bf16(aa, b_g2, ag[n], 0, 0, 0);
            }
        }
        #pragma unroll
        for (int n = 0; n < 4; ++n) {
            const int col = (4 * w + n) * 16 + lr;
            #pragma unroll
            for (int r = 0; r < 4; ++r) {
                const int row = m0 + 4 * lg + r;
                const float g = 1.f / (1.f + __expf(-ag[n][r]));
                out[(size_t)row * ND + col] = g * ao[n][r];
            }
        }
    }
}

// ---------------------------------------------------------------------------
// fallback: proven f32 kernel (used only if ws_size < WS_NEED)
// ---------------------------------------------------------------------------
__global__ __launch_bounds__(512, 2)
void stk_fused(const float* __restrict__ h,
               const int*   __restrict__ topk_idx,
               const float* __restrict__ topk_scores,
               const float* __restrict__ vW, const float* __restrict__ vb,
               const float* __restrict__ oW, const float* __restrict__ ob,
               const float* __restrict__ gW, const float* __restrict__ gb,
               float* __restrict__ out)
{
    __shared__ float s_attn[32][NK];
    __shared__ int   s_idx [32][NK];
    __shared__ float s_wsum[32][ND];
    __shared__ float s_h   [32][ND];
    __shared__ float s_agg [32][ND];

    const int t  = threadIdx.x;
    const int m0 = blockIdx.x * 32;
    const size_t hb = (size_t)(m0 >> 9) * NC * ND;

    {
        const int k  = t & 31;
        const int r0 = t >> 5;
        #pragma unroll
        for (int half = 0; half < 2; ++half) {
            const int r = r0 + (half << 4);
            const size_t off = (size_t)(m0 + r) * NK + k;
            const float s = topk_scores[off];
            const int  id = topk_idx[off];
            float m = s;
            #pragma unroll
            for (int msk = 16; msk >= 1; msk >>= 1) m = fmaxf(m, __shfl_xor(m, msk));
            const float p = __expf(s - m);
            float Z = p;
            #pragma unroll
            for (int msk = 16; msk >= 1; msk >>= 1) Z += __shfl_xor(Z, msk);
            s_attn[r][k] = p / Z;
            s_idx [r][k] = id;
        }
    }
    __syncthreads();

    const int d  = t & 127;
    const int rb = (t >> 7) * 8;

    #pragma unroll
    for (int i = 0; i < 8; ++i) {
        const int r = rb + i;
        const size_t ro = (size_t)(m0 + r) * ND;
        s_h[r][d]       = h[ro + d];
        s_h[r][d + 128] = h[ro + d + 128];
    }
    #pragma unroll 1
    for (int i = 0; i < 8; ++i) {
        const int r = rb + i;
        float a0 = 0.f, a1 = 0.f;
        #pragma unroll 8
        for (int k = 0; k < NK; ++k) {
            const float w  = s_attn[r][k];
            const size_t nb = hb + (size_t)s_idx[r][k] * ND;
            a0 = fmaf(w, h[nb + d],       a0);
            a1 = fmaf(w, h[nb + d + 128], a1);
        }
        s_wsum[r][d]       = a0;
        s_wsum[r][d + 128] = a1;
    }
    __syncthreads();

    float agg0[8], agg1[8];
    {
        const float b0 = vb[d], b1 = vb[d + 128];
        #pragma unroll
        for (int i = 0; i < 8; ++i) { agg0[i] = b0; agg1[i] = b1; }
        for (int e0 = 0; e0 < ND; e0 += 4) {
            float w0[4], w1[4];
            #pragma unroll
            for (int j = 0; j < 4; ++j) {
                w0[j] = vW[(size_t)(e0 + j) * ND + d];
                w1[j] = vW[(size_t)(e0 + j) * ND + d + 128];
            }
            #pragma unroll
            for (int i = 0; i < 8; ++i) {
                const float4 a = *reinterpret_cast<const float4*>(&s_wsum[rb + i][e0]);
                agg0[i] = fmaf(a.x, w0[0], agg0[i]); agg1[i] = fmaf(a.x, w1[0], agg1[i]);
                agg0[i] = fmaf(a.y, w0[1], agg0[i]); agg1[i] = fmaf(a.y, w1[1], agg1[i]);
                agg0[i] = fmaf(a.z, w0[2], agg0[i]); agg1[i] = fmaf(a.z, w1[2], agg1[i]);
                agg0[i] = fmaf(a.w, w0[3], agg0[i]); agg1[i] = fmaf(a.w, w1[3], agg1[i]);
            }
        }
        #pragma unroll
        for (int i = 0; i < 8; ++i) {
            s_agg[rb + i][d]       = agg0[i];
            s_agg[rb + i][d + 128] = agg1[i];
        }
    }
    __syncthreads();

    float o0[8], o1[8], g0[8], g1[8];
    {
        const float obb0 = ob[d], obb1 = ob[d + 128];
        const float gbb0 = gb[d], gbb1 = gb[d + 128];
        #pragma unroll
        for (int i = 0; i < 8; ++i) { o0[i]=obb0; o1[i]=obb1; g0[i]=gbb0; g1[i]=gbb1; }
        for (int e0 = 0; e0 < ND; e0 += 4) {
            float ow0[4], ow1[4], gh0[4], gh1[4], ga0[4], ga1[4];
            #pragma unroll
            for (int j = 0; j < 4; ++j) {
                const size_t er = (size_t)(e0 + j) * ND;
                ow0[j] = oW[er + d];                    ow1[j] = oW[er + d + 128];
                gh0[j] = gW[er + d];                    gh1[j] = gW[er + d + 128];
                ga0[j] = gW[er + (size_t)ND * ND + d];  ga1[j] = gW[er + (size_t)ND * ND + d + 128];
            }
            #pragma unroll
            for (int i = 0; i < 8; ++i) {
                const float4 a  = *reinterpret_cast<const float4*>(&s_agg[rb + i][e0]);
                const float4 hh = *reinterpret_cast<const float4*>(&s_h  [rb + i][e0]);
                o0[i] = fmaf(a.x, ow0[0], o0[i]); o0[i] = fmaf(a.y, ow0[1], o0[i]);
                o0[i] = fmaf(a.z, ow0[2], o0[i]); o0[i] = fmaf(a.w, ow0[3], o0[i]);
                o1[i] = fmaf(a.x, ow1[0], o1[i]); o1[i] = fmaf(a.y, ow1[1], o1[i]);
                o1[i] = fmaf(a.z, ow1[2], o1[i]); o1[i] = fmaf(a.w, ow1[3], o1[i]);
                g0[i] = fmaf(hh.x, gh0[0], g0[i]); g0[i] = fmaf(hh.y, gh0[1], g0[i]);
                g0[i] = fmaf(hh.z, gh0[2], g0[i]); g0[i] = fmaf(hh.w, gh0[3], g0[i]);
                g1[i] = fmaf(hh.x, gh1[0], g1[i]); g1[i] = fmaf(hh.y, gh1[1], g1[i]);
                g1[i] = fmaf(hh.z, gh1[2], g1[i]); g1[i] = fmaf(hh.w, gh1[3], g1[i]);
                g0[i] = fmaf(a.x, ga0[0], g0[i]); g0[i] = fmaf(a.y, ga0[1], g0[i]);
                g0[i] = fmaf(a.z, ga0[2], g0[i]); g0[i] = fmaf(a.w, ga0[3], g0[i]);
                g1[i] = fmaf(a.x, ga1[0], g1[i]); g1[i] = fmaf(a.y, ga1[1], g1[i]);
                g1[i] = fmaf(a.z, ga1[2], g1[i]); g1[i] = fmaf(a.w, ga1[3], g1[i]);
            }
        }
    }
    #pragma unroll
    for (int i = 0; i < 8; ++i) {
        const size_t ro = (size_t)(m0 + rb + i) * ND;
        const float sg0 = 1.f / (1.f + __expf(-g0[i]));
        const float sg1 = 1.f / (1.f + __expf(-g1[i]));
        out[ro + d]       = sg0 * o0[i];
        out[ro + d + 128] = sg1 * o1[i];
    }
}

extern "C" void kernel_launch(void* const* d_in, const int* in_sizes, int n_in,
                              void* d_out, int out_size, void* d_ws, size_t ws_size,
                              hipStream_t stream) {
    const float* h   = (const float*)d_in[0];
    const int*   idx = (const int*)  d_in[1];
    const float* sc  = (const float*)d_in[2];
    const float* vW  = (const float*)d_in[3];
    const float* vb  = (const float*)d_in[4];
    const float* oW  = (const float*)d_in[5];
    const float* ob  = (const float*)d_in[6];
    const float* gW  = (const float*)d_in[7];
    const float* gb  = (const float*)d_in[8];
    float* out = (float*)d_out;

    if (ws_size >= WS_NEED) {
        unsigned short* wsb = (unsigned short*)d_ws;
        stk_pack<<<128, 256, 0, stream>>>(vW, oW, gW, wsb);
        stk_mfma<<<NBLK, 256, 0, stream>>>(h, idx, sc, vb, ob, gb, wsb, out);
    } else {
        stk_fused<<<512 / 2, 512, 0, stream>>>(h, idx, sc, vW, vb, oW, ob, gW, gb, out);
    }
}

// Round 5
// 41.662 us; speedup vs baseline: 1.2289x; 1.2289x over previous
//
#include <hip/hip_runtime.h>
#include <hip/hip_bf16.h>
#include <cstdint>
#include <cstddef>

using short8  = __attribute__((ext_vector_type(8))) short;
using short4v = __attribute__((ext_vector_type(4))) short;
using f32x4   = __attribute__((ext_vector_type(4))) float;

constexpr int NB = 16, NC = 512, ND = 256, NK = 32;
constexpr int ROWS = 16;               // rows per block (one 16-row M tile)
constexpr int NROW = NB * NC;          // 8192
constexpr int NBLK = NROW / ROWS;      // 512
constexpr int LDP  = ND + 8;           // ushort row stride (528 B)
constexpr int PLD  = 516;              // P f32 row stride -> bank stride 4, 2-way (free)

// d_ws layout (bf16 element offsets):
//  vW frags [0,65536) ; oW [65536,131072) ; gW [131072,262144)
//  h  frags [262144, 262144+16*131072): per batch b, frag fs=ks*16+nt,
//     elem = PHB + b*131072 + ((ks*16+nt)*64 + lane)*8 + j
//          == h[b][ks*32+(lane>>4)*8+j][nt*16+(lane&15)]
constexpr int PVW = 0;
constexpr int POW = 65536;
constexpr int PGW = 131072;
constexpr int PHB = 262144;
constexpr size_t WS_NEED = (size_t)(PHB + NB * 131072) * 2;   // ~4.7 MB

static __device__ __forceinline__ unsigned short f2bf(float f) {
    __hip_bfloat16 b = __float2bfloat16(f);
    return *reinterpret_cast<unsigned short*>(&b);
}
static __device__ __forceinline__ short4v f2bf4(float4 v) {
    short4v r;
    r[0] = (short)f2bf(v.x); r[1] = (short)f2bf(v.y);
    r[2] = (short)f2bf(v.z); r[3] = (short)f2bf(v.w);
    return r;
}

// ---------------------------------------------------------------------------
// pack weights: vW/oW/gW (f32 row-major [K][N]) -> fragment-major bf16
// ---------------------------------------------------------------------------
__global__ __launch_bounds__(256)
void stk_pack(const float* __restrict__ vW, const float* __restrict__ oW,
              const float* __restrict__ gW, unsigned short* __restrict__ ws)
{
    const int tid  = blockIdx.x * 256 + threadIdx.x;   // 32768 threads
    const int lane = tid & 63;
    const int fl   = tid >> 6;                         // fragment id 0..511
    const float* src; int nt, ks;
    if (fl < 128)      { src = vW; nt = fl >> 3;         ks = fl & 7;          }
    else if (fl < 256) { src = oW; nt = (fl - 128) >> 3; ks = (fl - 128) & 7;  }
    else               { src = gW; nt = (fl - 256) >> 4; ks = (fl - 256) & 15; }
    const int col = nt * 16 + (lane & 15);
    const int k0  = ks * 32 + (lane >> 4) * 8;
    short8 v;
    #pragma unroll
    for (int j = 0; j < 8; ++j)
        v[j] = (short)f2bf(src[(size_t)(k0 + j) * ND + col]);
    *reinterpret_cast<short8*>(&ws[(size_t)tid * 8]) = v;
}

// ---------------------------------------------------------------------------
// pack h: [16][512][256] f32 -> per-batch B-fragment-major bf16 slab
// ---------------------------------------------------------------------------
__global__ __launch_bounds__(256)
void stk_pack_h(const float* __restrict__ h, unsigned short* __restrict__ ws)
{
    const int tid  = blockIdx.x * 256 + threadIdx.x;   // 262144 threads
    const int lane = tid & 63;
    const int fs   = tid >> 6;                         // 0..4095 = b*256 + ks*16 + nt
    const int b    = fs >> 8;
    const int ks   = (fs >> 4) & 15;
    const int nt   = fs & 15;
    const float* src = h + (size_t)b * NC * ND;
    const int col = nt * 16 + (lane & 15);
    const int k0  = ks * 32 + (lane >> 4) * 8;
    short8 v;
    #pragma unroll
    for (int j = 0; j < 8; ++j)
        v[j] = (short)f2bf(src[(size_t)(k0 + j) * ND + col]);
    *reinterpret_cast<short8*>(&ws[(size_t)PHB + (size_t)tid * 8]) = v;
}

// ---------------------------------------------------------------------------
// main fused kernel: 16 rows/block, 512 threads (8 waves), dense-P MFMA
// ---------------------------------------------------------------------------
__global__ __launch_bounds__(512, 2)
void stk_mfma(const float* __restrict__ h,
              const int*   __restrict__ topk_idx,
              const float* __restrict__ topk_scores,
              const float* __restrict__ vb, const float* __restrict__ ob,
              const float* __restrict__ gb,
              const unsigned short* __restrict__ wsb,
              float* __restrict__ out)
{
    __shared__ __align__(16) float          s_P [ROWS][PLD];   // dense attn matrix
    __shared__ __align__(16) unsigned short s_w [ROWS][LDP];   // wsum bf16
    __shared__ __align__(16) unsigned short s_hb[ROWS][LDP];   // h    bf16
    __shared__ __align__(16) unsigned short s_ab[ROWS][LDP];   // agg  bf16

    const int t     = threadIdx.x;
    const int m0    = blockIdx.x * ROWS;
    const int batch = m0 >> 9;                        // C=512 rows per batch

    // ---- zero P (flat float4: 16*516/4 = 2064 vectors) ---------------------
    {
        float4* p4 = reinterpret_cast<float4*>(&s_P[0][0]);
        #pragma unroll
        for (int i = 0; i < 5; ++i) {
            const int j = t + i * 512;
            if (j < (ROWS * PLD) / 4) p4[j] = float4{0.f, 0.f, 0.f, 0.f};
        }
    }

    // ---- stage-h loads issued early (consumed after softmax) ---------------
    const int sr  = t >> 5;           // row 0..15
    const int sc8 = (t & 31) * 8;     // col chunk
    const float4 h0 = *reinterpret_cast<const float4*>(&h[(size_t)(m0 + sr) * ND + sc8]);
    const float4 h1 = *reinterpret_cast<const float4*>(&h[(size_t)(m0 + sr) * ND + sc8 + 4]);

    // ---- softmax over K (width-32 butterflies; masks <32 stay in-group) ----
    const int k = t & 31;
    const int r = t >> 5;             // 0..15
    float att; int id;
    {
        const size_t off = (size_t)(m0 + r) * NK + k;
        const float s = topk_scores[off];
        id = topk_idx[off];
        float m = s;
        #pragma unroll
        for (int msk = 16; msk >= 1; msk >>= 1)
            m = fmaxf(m, __shfl_xor(m, msk));
        const float p = __expf(s - m);
        float Z = p;
        #pragma unroll
        for (int msk = 16; msk >= 1; msk >>= 1)
            Z += __shfl_xor(Z, msk);
        att = p / Z;
    }
    __syncthreads();                  // P zeroed everywhere

    // ---- scatter-add into dense P (ds_add_f32 handles duplicate idx) -------
    atomicAdd(&s_P[r][id], att);

    // ---- store staged h as bf16 --------------------------------------------
    *reinterpret_cast<short4v*>(&s_hb[sr][sc8])     = f2bf4(h0);
    *reinterpret_cast<short4v*>(&s_hb[sr][sc8 + 4]) = f2bf4(h1);
    __syncthreads();                  // P complete + s_hb complete

    const int lane = t & 63;
    const int w    = t >> 6;          // wave 0..7
    const int n0   = 2 * w;           // first N tile (2 per wave)
    const int lr   = lane & 15;
    const int lg   = lane >> 4;

    // ---- GEMM1: wsum = P @ h_batch (16 k-slices of 32 channels) ------------
    {
        f32x4 acc[2] = {f32x4{0,0,0,0}, f32x4{0,0,0,0}};
        const unsigned short* hf = wsb + (size_t)PHB + (size_t)batch * 131072;
        #pragma unroll
        for (int ks = 0; ks < 16; ++ks) {
            const int kb = ks * 32 + lg * 8;
            const float4 a0 = *reinterpret_cast<const float4*>(&s_P[lr][kb]);
            const float4 a1 = *reinterpret_cast<const float4*>(&s_P[lr][kb + 4]);
            short8 a;
            a[0] = (short)f2bf(a0.x); a[1] = (short)f2bf(a0.y);
            a[2] = (short)f2bf(a0.z); a[3] = (short)f2bf(a0.w);
            a[4] = (short)f2bf(a1.x); a[5] = (short)f2bf(a1.y);
            a[6] = (short)f2bf(a1.z); a[7] = (short)f2bf(a1.w);
            #pragma unroll
            for (int n = 0; n < 2; ++n) {
                const short8 b = *reinterpret_cast<const short8*>(
                    &hf[(size_t)(((ks * 16 + n0 + n) * 64 + lane) * 8)]);
                acc[n] = __builtin_amdgcn_mfma_f32_16x16x32_bf16(a, b, acc[n], 0, 0, 0);
            }
        }
        #pragma unroll
        for (int n = 0; n < 2; ++n) {
            const int col = (n0 + n) * 16 + lr;
            #pragma unroll
            for (int q = 0; q < 4; ++q)
                s_w[4 * lg + q][col] = f2bf(acc[n][q]);
        }
    }
    __syncthreads();

    // ---- GEMM2: agg = wsum @ vW + vb ---------------------------------------
    {
        f32x4 acc[2];
        #pragma unroll
        for (int n = 0; n < 2; ++n) {
            const float bv = vb[(n0 + n) * 16 + lr];
            acc[n] = f32x4{bv, bv, bv, bv};
        }
        #pragma unroll
        for (int ks = 0; ks < 8; ++ks) {
            const int kb = ks * 32 + lg * 8;
            const short8 a = *reinterpret_cast<const short8*>(&s_w[lr][kb]);
            #pragma unroll
            for (int n = 0; n < 2; ++n) {
                const short8 b = *reinterpret_cast<const short8*>(
                    &wsb[(size_t)(PVW + (((n0 + n) * 8 + ks) * 64 + lane) * 8)]);
                acc[n] = __builtin_amdgcn_mfma_f32_16x16x32_bf16(a, b, acc[n], 0, 0, 0);
            }
        }
        #pragma unroll
        for (int n = 0; n < 2; ++n) {
            const int col = (n0 + n) * 16 + lr;
            #pragma unroll
            for (int q = 0; q < 4; ++q)
                s_ab[4 * lg + q][col] = f2bf(acc[n][q]);
        }
    }
    __syncthreads();

    // ---- GEMM3: o = agg@oW + ob ; g = h@gW_h + agg@gW_a + gb ; epilogue ----
    {
        f32x4 ao[2], ag[2];
        #pragma unroll
        for (int n = 0; n < 2; ++n) {
            const float bo = ob[(n0 + n) * 16 + lr];
            const float bg = gb[(n0 + n) * 16 + lr];
            ao[n] = f32x4{bo, bo, bo, bo};
            ag[n] = f32x4{bg, bg, bg, bg};
        }
        #pragma unroll
        for (int ks = 0; ks < 8; ++ks) {
            const int kb = ks * 32 + lg * 8;
            const short8 aa = *reinterpret_cast<const short8*>(&s_ab[lr][kb]);
            const short8 ah = *reinterpret_cast<const short8*>(&s_hb[lr][kb]);
            #pragma unroll
            for (int n = 0; n < 2; ++n) {
                const int nt = n0 + n;
                const short8 b_o  = *reinterpret_cast<const short8*>(
                    &wsb[(size_t)(POW + ((nt * 8 + ks) * 64 + lane) * 8)]);
                const short8 b_g1 = *reinterpret_cast<const short8*>(
                    &wsb[(size_t)(PGW + ((nt * 16 + ks) * 64 + lane) * 8)]);
                const short8 b_g2 = *reinterpret_cast<const short8*>(
                    &wsb[(size_t)(PGW + ((nt * 16 + ks + 8) * 64 + lane) * 8)]);
                ao[n] = __builtin_amdgcn_mfma_f32_16x16x32_bf16(aa, b_o,  ao[n], 0, 0, 0);
                ag[n] = __builtin_amdgcn_mfma_f32_16x16x32_bf16(ah, b_g1, ag[n], 0, 0, 0);
                ag[n] = __builtin_amdgcn_mfma_f32_16x16x32_bf16(aa, b_g2, ag[n], 0, 0, 0);
            }
        }
        #pragma unroll
        for (int n = 0; n < 2; ++n) {
            const int col = (n0 + n) * 16 + lr;
            #pragma unroll
            for (int q = 0; q < 4; ++q) {
                const int row = m0 + 4 * lg + q;
                const float g = 1.f / (1.f + __expf(-ag[n][q]));
                out[(size_t)row * ND + col] = g * ao[n][q];
            }
        }
    }
}

// ---------------------------------------------------------------------------
// fallback: proven f32 kernel (used only if ws_size < WS_NEED)
// ---------------------------------------------------------------------------
__global__ __launch_bounds__(512, 2)
void stk_fused(const float* __restrict__ h,
               const int*   __restrict__ topk_idx,
               const float* __restrict__ topk_scores,
               const float* __restrict__ vW, const float* __restrict__ vb,
               const float* __restrict__ oW, const float* __restrict__ ob,
               const float* __restrict__ gW, const float* __restrict__ gb,
               float* __restrict__ out)
{
    __shared__ float s_attn[32][NK];
    __shared__ int   s_idx [32][NK];
    __shared__ float s_wsum[32][ND];
    __shared__ float s_h   [32][ND];
    __shared__ float s_agg [32][ND];

    const int t  = threadIdx.x;
    const int m0 = blockIdx.x * 32;
    const size_t hb = (size_t)(m0 >> 9) * NC * ND;

    {
        const int k  = t & 31;
        const int r0 = t >> 5;
        #pragma unroll
        for (int half = 0; half < 2; ++half) {
            const int r = r0 + (half << 4);
            const size_t off = (size_t)(m0 + r) * NK + k;
            const float s = topk_scores[off];
            const int  id = topk_idx[off];
            float m = s;
            #pragma unroll
            for (int msk = 16; msk >= 1; msk >>= 1) m = fmaxf(m, __shfl_xor(m, msk));
            const float p = __expf(s - m);
            float Z = p;
            #pragma unroll
            for (int msk = 16; msk >= 1; msk >>= 1) Z += __shfl_xor(Z, msk);
            s_attn[r][k] = p / Z;
            s_idx [r][k] = id;
        }
    }
    __syncthreads();

    const int d  = t & 127;
    const int rb = (t >> 7) * 8;

    #pragma unroll
    for (int i = 0; i < 8; ++i) {
        const int r = rb + i;
        const size_t ro = (size_t)(m0 + r) * ND;
        s_h[r][d]       = h[ro + d];
        s_h[r][d + 128] = h[ro + d + 128];
    }
    #pragma unroll 1
    for (int i = 0; i < 8; ++i) {
        const int r = rb + i;
        float a0 = 0.f, a1 = 0.f;
        #pragma unroll 8
        for (int k = 0; k < NK; ++k) {
            const float w  = s_attn[r][k];
            const size_t nb = hb + (size_t)s_idx[r][k] * ND;
            a0 = fmaf(w, h[nb + d],       a0);
            a1 = fmaf(w, h[nb + d + 128], a1);
        }
        s_wsum[r][d]       = a0;
        s_wsum[r][d + 128] = a1;
    }
    __syncthreads();

    float agg0[8], agg1[8];
    {
        const float b0 = vb[d], b1 = vb[d + 128];
        #pragma unroll
        for (int i = 0; i < 8; ++i) { agg0[i] = b0; agg1[i] = b1; }
        for (int e0 = 0; e0 < ND; e0 += 4) {
            float w0[4], w1[4];
            #pragma unroll
            for (int j = 0; j < 4; ++j) {
                w0[j] = vW[(size_t)(e0 + j) * ND + d];
                w1[j] = vW[(size_t)(e0 + j) * ND + d + 128];
            }
            #pragma unroll
            for (int i = 0; i < 8; ++i) {
                const float4 a = *reinterpret_cast<const float4*>(&s_wsum[rb + i][e0]);
                agg0[i] = fmaf(a.x, w0[0], agg0[i]); agg1[i] = fmaf(a.x, w1[0], agg1[i]);
                agg0[i] = fmaf(a.y, w0[1], agg0[i]); agg1[i] = fmaf(a.y, w1[1], agg1[i]);
                agg0[i] = fmaf(a.z, w0[2], agg0[i]); agg1[i] = fmaf(a.z, w1[2], agg1[i]);
                agg0[i] = fmaf(a.w, w0[3], agg0[i]); agg1[i] = fmaf(a.w, w1[3], agg1[i]);
            }
        }
        #pragma unroll
        for (int i = 0; i < 8; ++i) {
            s_agg[rb + i][d]       = agg0[i];
            s_agg[rb + i][d + 128] = agg1[i];
        }
    }
    __syncthreads();

    float o0[8], o1[8], g0[8], g1[8];
    {
        const float obb0 = ob[d], obb1 = ob[d + 128];
        const float gbb0 = gb[d], gbb1 = gb[d + 128];
        #pragma unroll
        for (int i = 0; i < 8; ++i) { o0[i]=obb0; o1[i]=obb1; g0[i]=gbb0; g1[i]=gbb1; }
        for (int e0 = 0; e0 < ND; e0 += 4) {
            float ow0[4], ow1[4], gh0[4], gh1[4], ga0[4], ga1[4];
            #pragma unroll
            for (int j = 0; j < 4; ++j) {
                const size_t er = (size_t)(e0 + j) * ND;
                ow0[j] = oW[er + d];                    ow1[j] = oW[er + d + 128];
                gh0[j] = gW[er + d];                    gh1[j] = gW[er + d + 128];
                ga0[j] = gW[er + (size_t)ND * ND + d];  ga1[j] = gW[er + (size_t)ND * ND + d + 128];
            }
            #pragma unroll
            for (int i = 0; i < 8; ++i) {
                const float4 a  = *reinterpret_cast<const float4*>(&s_agg[rb + i][e0]);
                const float4 hh = *reinterpret_cast<const float4*>(&s_h  [rb + i][e0]);
                o0[i] = fmaf(a.x, ow0[0], o0[i]); o0[i] = fmaf(a.y, ow0[1], o0[i]);
                o0[i] = fmaf(a.z, ow0[2], o0[i]); o0[i] = fmaf(a.w, ow0[3], o0[i]);
                o1[i] = fmaf(a.x, ow1[0], o1[i]); o1[i] = fmaf(a.y, ow1[1], o1[i]);
                o1[i] = fmaf(a.z, ow1[2], o1[i]); o1[i] = fmaf(a.w, ow1[3], o1[i]);
                g0[i] = fmaf(hh.x, gh0[0], g0[i]); g0[i] = fmaf(hh.y, gh0[1], g0[i]);
                g0[i] = fmaf(hh.z, gh0[2], g0[i]); g0[i] = fmaf(hh.w, gh0[3], g0[i]);
                g1[i] = fmaf(hh.x, gh1[0], g1[i]); g1[i] = fmaf(hh.y, gh1[1], g1[i]);
                g1[i] = fmaf(hh.z, gh1[2], g1[i]); g1[i] = fmaf(hh.w, gh1[3], g1[i]);
                g0[i] = fmaf(a.x, ga0[0], g0[i]); g0[i] = fmaf(a.y, ga0[1], g0[i]);
                g0[i] = fmaf(a.z, ga0[2], g0[i]); g0[i] = fmaf(a.w, ga0[3], g0[i]);
                g1[i] = fmaf(a.x, ga1[0], g1[i]); g1[i] = fmaf(a.y, ga1[1], g1[i]);
                g1[i] = fmaf(a.z, ga1[2], g1[i]); g1[i] = fmaf(a.w, ga1[3], g1[i]);
            }
        }
    }
    #pragma unroll
    for (int i = 0; i < 8; ++i) {
        const size_t ro = (size_t)(m0 + rb + i) * ND;
        const float sg0 = 1.f / (1.f + __expf(-g0[i]));
        const float sg1 = 1.f / (1.f + __expf(-g1[i]));
        out[ro + d]       = sg0 * o0[i];
        out[ro + d + 128] = sg1 * o1[i];
    }
}

extern "C" void kernel_launch(void* const* d_in, const int* in_sizes, int n_in,
                              void* d_out, int out_size, void* d_ws, size_t ws_size,
                              hipStream_t stream) {
    const float* h   = (const float*)d_in[0];
    const int*   idx = (const int*)  d_in[1];
    const float* sc  = (const float*)d_in[2];
    const float* vW  = (const float*)d_in[3];
    const float* vb  = (const float*)d_in[4];
    const float* oW  = (const float*)d_in[5];
    const float* ob  = (const float*)d_in[6];
    const float* gW  = (const float*)d_in[7];
    const float* gb  = (const float*)d_in[8];
    float* out = (float*)d_out;

    if (ws_size >= WS_NEED) {
        unsigned short* wsb = (unsigned short*)d_ws;
        stk_pack  <<<128,  256, 0, stream>>>(vW, oW, gW, wsb);
        stk_pack_h<<<1024, 256, 0, stream>>>(h, wsb);
        stk_mfma  <<<NBLK, 512, 0, stream>>>(h, idx, sc, vb, ob, gb, wsb, out);
    } else {
        stk_fused<<<256, 512, 0, stream>>>(h, idx, sc, vW, vb, oW, ob, gW, gb, out);
    }
}

// Round 6
// 31.848 us; speedup vs baseline: 1.6076x; 1.3081x over previous
//
#include <hip/hip_runtime.h>
#include <hip/hip_bf16.h>
#include <cstdint>
#include <cstddef>

using short8  = __attribute__((ext_vector_type(8))) short;
using short4v = __attribute__((ext_vector_type(4))) short;
using f32x4   = __attribute__((ext_vector_type(4))) float;

constexpr int NB = 16, NC = 512, ND = 256, NK = 32;
constexpr int ROWS = 16;               // rows per block (one 16-row M tile)
constexpr int NROW = NB * NC;          // 8192
constexpr int NBLK = NROW / ROWS;      // 512
constexpr int LDP  = ND + 8;           // ushort row stride (528 B)
constexpr int PLD  = 516;              // P f32 row stride -> 2-way banks (free)

// LDS union layout (bytes): [P f32 16x516 | union s_ab 16x528 bf16] [s_w] [s_hb]
constexpr int LDS_W   = 16 * PLD * 4;              // 33024
constexpr int LDS_HB  = LDS_W + 16 * LDP * 2;      // +16896
constexpr int LDS_TOT = LDS_HB + 16 * LDP * 2;     // 66816 -> 2 blocks/CU

// d_ws layout (bf16 element offsets):
//  vW frags [0,65536) ; oW [65536,131072) ; gW [131072,262144)
//  h  frags [262144 + b*131072): frag fs=ks*16+nt,
//     elem = PHB + b*131072 + ((ks*16+nt)*64 + lane)*8 + j
//          == h[b][ks*32+(lane>>4)*8+j][nt*16+(lane&15)]
constexpr int PVW = 0;
constexpr int POW = 65536;
constexpr int PGW = 131072;
constexpr int PHB = 262144;
constexpr size_t WS_NEED = (size_t)(PHB + NB * 131072) * 2;   // ~4.7 MB

static __device__ __forceinline__ unsigned short f2bf(float f) {
    __hip_bfloat16 b = __float2bfloat16(f);
    return *reinterpret_cast<unsigned short*>(&b);
}
static __device__ __forceinline__ short4v f2bf4(float4 v) {
    short4v r;
    r[0] = (short)f2bf(v.x); r[1] = (short)f2bf(v.y);
    r[2] = (short)f2bf(v.z); r[3] = (short)f2bf(v.w);
    return r;
}

// ---------------------------------------------------------------------------
// merged pack: blocks 0..127 pack vW/oW/gW; blocks 128..1151 pack h
// ---------------------------------------------------------------------------
__global__ __launch_bounds__(256)
void stk_pack_all(const float* __restrict__ vW, const float* __restrict__ oW,
                  const float* __restrict__ gW, const float* __restrict__ h,
                  unsigned short* __restrict__ ws)
{
    const int blk = blockIdx.x;
    if (blk < 128) {
        const int tid  = blk * 256 + threadIdx.x;      // 32768 threads
        const int lane = tid & 63;
        const int fl   = tid >> 6;                     // fragment id 0..511
        const float* src; int nt, ks;
        if (fl < 128)      { src = vW; nt = fl >> 3;         ks = fl & 7;          }
        else if (fl < 256) { src = oW; nt = (fl - 128) >> 3; ks = (fl - 128) & 7;  }
        else               { src = gW; nt = (fl - 256) >> 4; ks = (fl - 256) & 15; }
        const int col = nt * 16 + (lane & 15);
        const int k0  = ks * 32 + (lane >> 4) * 8;
        short8 v;
        #pragma unroll
        for (int j = 0; j < 8; ++j)
            v[j] = (short)f2bf(src[(size_t)(k0 + j) * ND + col]);
        *reinterpret_cast<short8*>(&ws[(size_t)tid * 8]) = v;
    } else {
        const int tid  = (blk - 128) * 256 + threadIdx.x;   // 262144 threads
        const int lane = tid & 63;
        const int fs   = tid >> 6;                     // b*256 + ks*16 + nt
        const int b    = fs >> 8;
        const int ks   = (fs >> 4) & 15;
        const int nt   = fs & 15;
        const float* src = h + (size_t)b * NC * ND;
        const int col = nt * 16 + (lane & 15);
        const int k0  = ks * 32 + (lane >> 4) * 8;
        short8 v;
        #pragma unroll
        for (int j = 0; j < 8; ++j)
            v[j] = (short)f2bf(src[(size_t)(k0 + j) * ND + col]);
        *reinterpret_cast<short8*>(&ws[(size_t)PHB + (size_t)tid * 8]) = v;
    }
}

// ---------------------------------------------------------------------------
// main fused kernel: 16 rows/block, 512 threads (8 waves), dense-P MFMA
// ---------------------------------------------------------------------------
__global__ __launch_bounds__(512, 4)
void stk_mfma(const float* __restrict__ h,
              const int*   __restrict__ topk_idx,
              const float* __restrict__ topk_scores,
              const float* __restrict__ vb, const float* __restrict__ ob,
              const float* __restrict__ gb,
              const unsigned short* __restrict__ wsb,
              float* __restrict__ out)
{
    __shared__ __align__(16) char smem[LDS_TOT];
    float          (*s_P )[PLD] = reinterpret_cast<float(*)[PLD]>(smem);
    unsigned short (*s_ab)[LDP] = reinterpret_cast<unsigned short(*)[LDP]>(smem); // union w/ P
    unsigned short (*s_w )[LDP] = reinterpret_cast<unsigned short(*)[LDP]>(smem + LDS_W);
    unsigned short (*s_hb)[LDP] = reinterpret_cast<unsigned short(*)[LDP]>(smem + LDS_HB);

    const int t     = threadIdx.x;
    // XCD-aware bijective swizzle: 512 blocks, 8 XCDs -> 64 consecutive tiles
    // (= 2 batches) per XCD, keeping h-slab + weights L2-resident per XCD.
    const int bid   = (int)blockIdx.x;
    const int swz   = ((bid & 7) << 6) + (bid >> 3);
    const int m0    = swz * ROWS;
    const int batch = m0 >> 9;                        // C=512 rows per batch

    // ---- zero P (flat float4: 16*516/4 = 2064 vectors) ---------------------
    {
        float4* p4 = reinterpret_cast<float4*>(&s_P[0][0]);
        #pragma unroll
        for (int i = 0; i < 5; ++i) {
            const int j = t + i * 512;
            if (j < (ROWS * PLD) / 4) p4[j] = float4{0.f, 0.f, 0.f, 0.f};
        }
    }

    // ---- stage-h loads issued early (consumed after softmax) ---------------
    const int sr  = t >> 5;           // row 0..15
    const int sc8 = (t & 31) * 8;     // col chunk
    const float4 h0 = *reinterpret_cast<const float4*>(&h[(size_t)(m0 + sr) * ND + sc8]);
    const float4 h1 = *reinterpret_cast<const float4*>(&h[(size_t)(m0 + sr) * ND + sc8 + 4]);

    // ---- softmax over K (width-32 butterflies) -----------------------------
    const int k = t & 31;
    const int r = t >> 5;             // 0..15
    float att; int id;
    {
        const size_t off = (size_t)(m0 + r) * NK + k;
        const float s = topk_scores[off];
        id = topk_idx[off];
        float m = s;
        #pragma unroll
        for (int msk = 16; msk >= 1; msk >>= 1)
            m = fmaxf(m, __shfl_xor(m, msk));
        const float p = __expf(s - m);
        float Z = p;
        #pragma unroll
        for (int msk = 16; msk >= 1; msk >>= 1)
            Z += __shfl_xor(Z, msk);
        att = p / Z;
    }
    __syncthreads();                  // P zeroed everywhere

    // ---- scatter-add into dense P (ds_add handles duplicate idx) -----------
    atomicAdd(&s_P[r][id], att);

    // ---- store staged h as bf16 --------------------------------------------
    *reinterpret_cast<short4v*>(&s_hb[sr][sc8])     = f2bf4(h0);
    *reinterpret_cast<short4v*>(&s_hb[sr][sc8 + 4]) = f2bf4(h1);
    __syncthreads();                  // P complete + s_hb complete

    const int lane = t & 63;
    const int w    = t >> 6;          // wave 0..7
    const int n0   = 2 * w;           // first N tile (2 per wave)
    const int lr   = lane & 15;
    const int lg   = lane >> 4;

    // ---- GEMM1: wsum = P @ h_batch (16 k-slices of 32 channels) ------------
    {
        f32x4 acc[2] = {f32x4{0,0,0,0}, f32x4{0,0,0,0}};
        const unsigned short* hf = wsb + (size_t)PHB + (size_t)batch * 131072;
        #pragma unroll
        for (int ks = 0; ks < 16; ++ks) {
            const int kb = ks * 32 + lg * 8;
            const float4 a0 = *reinterpret_cast<const float4*>(&s_P[lr][kb]);
            const float4 a1 = *reinterpret_cast<const float4*>(&s_P[lr][kb + 4]);
            short8 a;
            a[0] = (short)f2bf(a0.x); a[1] = (short)f2bf(a0.y);
            a[2] = (short)f2bf(a0.z); a[3] = (short)f2bf(a0.w);
            a[4] = (short)f2bf(a1.x); a[5] = (short)f2bf(a1.y);
            a[6] = (short)f2bf(a1.z); a[7] = (short)f2bf(a1.w);
            #pragma unroll
            for (int n = 0; n < 2; ++n) {
                const short8 b = *reinterpret_cast<const short8*>(
                    &hf[(size_t)(((ks * 16 + n0 + n) * 64 + lane) * 8)]);
                acc[n] = __builtin_amdgcn_mfma_f32_16x16x32_bf16(a, b, acc[n], 0, 0, 0);
            }
        }
        #pragma unroll
        for (int n = 0; n < 2; ++n) {
            const int col = (n0 + n) * 16 + lr;
            #pragma unroll
            for (int q = 0; q < 4; ++q)
                s_w[4 * lg + q][col] = f2bf(acc[n][q]);
        }
    }
    __syncthreads();                  // s_w ready; s_P reads done (s_ab may overwrite)

    // ---- GEMM2: agg = wsum @ vW + vb ---------------------------------------
    {
        f32x4 acc[2];
        #pragma unroll
        for (int n = 0; n < 2; ++n) {
            const float bv = vb[(n0 + n) * 16 + lr];
            acc[n] = f32x4{bv, bv, bv, bv};
        }
        #pragma unroll
        for (int ks = 0; ks < 8; ++ks) {
            const int kb = ks * 32 + lg * 8;
            const short8 a = *reinterpret_cast<const short8*>(&s_w[lr][kb]);
            #pragma unroll
            for (int n = 0; n < 2; ++n) {
                const short8 b = *reinterpret_cast<const short8*>(
                    &wsb[(size_t)(PVW + (((n0 + n) * 8 + ks) * 64 + lane) * 8)]);
                acc[n] = __builtin_amdgcn_mfma_f32_16x16x32_bf16(a, b, acc[n], 0, 0, 0);
            }
        }
        #pragma unroll
        for (int n = 0; n < 2; ++n) {
            const int col = (n0 + n) * 16 + lr;
            #pragma unroll
            for (int q = 0; q < 4; ++q)
                s_ab[4 * lg + q][col] = f2bf(acc[n][q]);
        }
    }
    __syncthreads();

    // ---- GEMM3: o = agg@oW + ob ; g = h@gW_h + agg@gW_a + gb ; epilogue ----
    {
        f32x4 ao[2], ag[2];
        #pragma unroll
        for (int n = 0; n < 2; ++n) {
            const float bo = ob[(n0 + n) * 16 + lr];
            const float bg = gb[(n0 + n) * 16 + lr];
            ao[n] = f32x4{bo, bo, bo, bo};
            ag[n] = f32x4{bg, bg, bg, bg};
        }
        #pragma unroll
        for (int ks = 0; ks < 8; ++ks) {
            const int kb = ks * 32 + lg * 8;
            const short8 aa = *reinterpret_cast<const short8*>(&s_ab[lr][kb]);
            const short8 ah = *reinterpret_cast<const short8*>(&s_hb[lr][kb]);
            #pragma unroll
            for (int n = 0; n < 2; ++n) {
                const int nt = n0 + n;
                const short8 b_o  = *reinterpret_cast<const short8*>(
                    &wsb[(size_t)(POW + ((nt * 8 + ks) * 64 + lane) * 8)]);
                const short8 b_g1 = *reinterpret_cast<const short8*>(
                    &wsb[(size_t)(PGW + ((nt * 16 + ks) * 64 + lane) * 8)]);
                const short8 b_g2 = *reinterpret_cast<const short8*>(
                    &wsb[(size_t)(PGW + ((nt * 16 + ks + 8) * 64 + lane) * 8)]);
                ao[n] = __builtin_amdgcn_mfma_f32_16x16x32_bf16(aa, b_o,  ao[n], 0, 0, 0);
                ag[n] = __builtin_amdgcn_mfma_f32_16x16x32_bf16(ah, b_g1, ag[n], 0, 0, 0);
                ag[n] = __builtin_amdgcn_mfma_f32_16x16x32_bf16(aa, b_g2, ag[n], 0, 0, 0);
            }
        }
        #pragma unroll
        for (int n = 0; n < 2; ++n) {
            const int col = (n0 + n) * 16 + lr;
            #pragma unroll
            for (int q = 0; q < 4; ++q) {
                const int row = m0 + 4 * lg + q;
                const float g = 1.f / (1.f + __expf(-ag[n][q]));
                out[(size_t)row * ND + col] = g * ao[n][q];
            }
        }
    }
}

// ---------------------------------------------------------------------------
// fallback: proven f32 kernel (used only if ws_size < WS_NEED)
// ---------------------------------------------------------------------------
__global__ __launch_bounds__(512, 2)
void stk_fused(const float* __restrict__ h,
               const int*   __restrict__ topk_idx,
               const float* __restrict__ topk_scores,
               const float* __restrict__ vW, const float* __restrict__ vb,
               const float* __restrict__ oW, const float* __restrict__ ob,
               const float* __restrict__ gW, const float* __restrict__ gb,
               float* __restrict__ out)
{
    __shared__ float s_attn[32][NK];
    __shared__ int   s_idx [32][NK];
    __shared__ float s_wsum[32][ND];
    __shared__ float s_h   [32][ND];
    __shared__ float s_agg [32][ND];

    const int t  = threadIdx.x;
    const int m0 = blockIdx.x * 32;
    const size_t hb = (size_t)(m0 >> 9) * NC * ND;

    {
        const int k  = t & 31;
        const int r0 = t >> 5;
        #pragma unroll
        for (int half = 0; half < 2; ++half) {
            const int r = r0 + (half << 4);
            const size_t off = (size_t)(m0 + r) * NK + k;
            const float s = topk_scores[off];
            const int  id = topk_idx[off];
            float m = s;
            #pragma unroll
            for (int msk = 16; msk >= 1; msk >>= 1) m = fmaxf(m, __shfl_xor(m, msk));
            const float p = __expf(s - m);
            float Z = p;
            #pragma unroll
            for (int msk = 16; msk >= 1; msk >>= 1) Z += __shfl_xor(Z, msk);
            s_attn[r][k] = p / Z;
            s_idx [r][k] = id;
        }
    }
    __syncthreads();

    const int d  = t & 127;
    const int rb = (t >> 7) * 8;

    #pragma unroll
    for (int i = 0; i < 8; ++i) {
        const int r = rb + i;
        const size_t ro = (size_t)(m0 + r) * ND;
        s_h[r][d]       = h[ro + d];
        s_h[r][d + 128] = h[ro + d + 128];
    }
    #pragma unroll 1
    for (int i = 0; i < 8; ++i) {
        const int r = rb + i;
        float a0 = 0.f, a1 = 0.f;
        #pragma unroll 8
        for (int k = 0; k < NK; ++k) {
            const float w  = s_attn[r][k];
            const size_t nb = hb + (size_t)s_idx[r][k] * ND;
            a0 = fmaf(w, h[nb + d],       a0);
            a1 = fmaf(w, h[nb + d + 128], a1);
        }
        s_wsum[r][d]       = a0;
        s_wsum[r][d + 128] = a1;
    }
    __syncthreads();

    float agg0[8], agg1[8];
    {
        const float b0 = vb[d], b1 = vb[d + 128];
        #pragma unroll
        for (int i = 0; i < 8; ++i) { agg0[i] = b0; agg1[i] = b1; }
        for (int e0 = 0; e0 < ND; e0 += 4) {
            float w0[4], w1[4];
            #pragma unroll
            for (int j = 0; j < 4; ++j) {
                w0[j] = vW[(size_t)(e0 + j) * ND + d];
                w1[j] = vW[(size_t)(e0 + j) * ND + d + 128];
            }
            #pragma unroll
            for (int i = 0; i < 8; ++i) {
                const float4 a = *reinterpret_cast<const float4*>(&s_wsum[rb + i][e0]);
                agg0[i] = fmaf(a.x, w0[0], agg0[i]); agg1[i] = fmaf(a.x, w1[0], agg1[i]);
                agg0[i] = fmaf(a.y, w0[1], agg0[i]); agg1[i] = fmaf(a.y, w1[1], agg1[i]);
                agg0[i] = fmaf(a.z, w0[2], agg0[i]); agg1[i] = fmaf(a.z, w1[2], agg1[i]);
                agg0[i] = fmaf(a.w, w0[3], agg0[i]); agg1[i] = fmaf(a.w, w1[3], agg1[i]);
            }
        }
        #pragma unroll
        for (int i = 0; i < 8; ++i) {
            s_agg[rb + i][d]       = agg0[i];
            s_agg[rb + i][d + 128] = agg1[i];
        }
    }
    __syncthreads();

    float o0[8], o1[8], g0[8], g1[8];
    {
        const float obb0 = ob[d], obb1 = ob[d + 128];
        const float gbb0 = gb[d], gbb1 = gb[d + 128];
        #pragma unroll
        for (int i = 0; i < 8; ++i) { o0[i]=obb0; o1[i]=obb1; g0[i]=gbb0; g1[i]=gbb1; }
        for (int e0 = 0; e0 < ND; e0 += 4) {
            float ow0[4], ow1[4], gh0[4], gh1[4], ga0[4], ga1[4];
            #pragma unroll
            for (int j = 0; j < 4; ++j) {
                const size_t er = (size_t)(e0 + j) * ND;
                ow0[j] = oW[er + d];                    ow1[j] = oW[er + d + 128];
                gh0[j] = gW[er + d];                    gh1[j] = gW[er + d + 128];
                ga0[j] = gW[er + (size_t)ND * ND + d];  ga1[j] = gW[er + (size_t)ND * ND + d + 128];
            }
            #pragma unroll
            for (int i = 0; i < 8; ++i) {
                const float4 a  = *reinterpret_cast<const float4*>(&s_agg[rb + i][e0]);
                const float4 hh = *reinterpret_cast<const float4*>(&s_h  [rb + i][e0]);
                o0[i] = fmaf(a.x, ow0[0], o0[i]); o0[i] = fmaf(a.y, ow0[1], o0[i]);
                o0[i] = fmaf(a.z, ow0[2], o0[i]); o0[i] = fmaf(a.w, ow0[3], o0[i]);
                o1[i] = fmaf(a.x, ow1[0], o1[i]); o1[i] = fmaf(a.y, ow1[1], o1[i]);
                o1[i] = fmaf(a.z, ow1[2], o1[i]); o1[i] = fmaf(a.w, ow1[3], o1[i]);
                g0[i] = fmaf(hh.x, gh0[0], g0[i]); g0[i] = fmaf(hh.y, gh0[1], g0[i]);
                g0[i] = fmaf(hh.z, gh0[2], g0[i]); g0[i] = fmaf(hh.w, gh0[3], g0[i]);
                g1[i] = fmaf(hh.x, gh1[0], g1[i]); g1[i] = fmaf(hh.y, gh1[1], g1[i]);
                g1[i] = fmaf(hh.z, gh1[2], g1[i]); g1[i] = fmaf(hh.w, gh1[3], g1[i]);
                g0[i] = fmaf(a.x, ga0[0], g0[i]); g0[i] = fmaf(a.y, ga0[1], g0[i]);
                g0[i] = fmaf(a.z, ga0[2], g0[i]); g0[i] = fmaf(a.w, ga0[3], g0[i]);
                g1[i] = fmaf(a.x, ga1[0], g1[i]); g1[i] = fmaf(a.y, ga1[1], g1[i]);
                g1[i] = fmaf(a.z, ga1[2], g1[i]); g1[i] = fmaf(a.w, ga1[3], g1[i]);
            }
        }
    }
    #pragma unroll
    for (int i = 0; i < 8; ++i) {
        const size_t ro = (size_t)(m0 + rb + i) * ND;
        const float sg0 = 1.f / (1.f + __expf(-g0[i]));
        const float sg1 = 1.f / (1.f + __expf(-g1[i]));
        out[ro + d]       = sg0 * o0[i];
        out[ro + d + 128] = sg1 * o1[i];
    }
}

extern "C" void kernel_launch(void* const* d_in, const int* in_sizes, int n_in,
                              void* d_out, int out_size, void* d_ws, size_t ws_size,
                              hipStream_t stream) {
    const float* h   = (const float*)d_in[0];
    const int*   idx = (const int*)  d_in[1];
    const float* sc  = (const float*)d_in[2];
    const float* vW  = (const float*)d_in[3];
    const float* vb  = (const float*)d_in[4];
    const float* oW  = (const float*)d_in[5];
    const float* ob  = (const float*)d_in[6];
    const float* gW  = (const float*)d_in[7];
    const float* gb  = (const float*)d_in[8];
    float* out = (float*)d_out;

    if (ws_size >= WS_NEED) {
        unsigned short* wsb = (unsigned short*)d_ws;
        stk_pack_all<<<1152, 256, 0, stream>>>(vW, oW, gW, h, wsb);
        stk_mfma    <<<NBLK, 512, 0, stream>>>(h, idx, sc, vb, ob, gb, wsb, out);
    } else {
        stk_fused<<<256, 512, 0, stream>>>(h, idx, sc, vW, vb, oW, ob, gW, gb, out);
    }
}